// Round 7
// baseline (303.754 us; speedup 1.0000x reference)
//
#include <hip/hip_runtime.h>
#include <hip/hip_bf16.h>
#include <stdint.h>

typedef short bf16x8 __attribute__((ext_vector_type(8)));
typedef short bf16x4 __attribute__((ext_vector_type(4)));
typedef float f32x4 __attribute__((ext_vector_type(4)));

#define BHC 64     // B*H
#define NQ 2048    // sequence length
#define DD 64      // head dim
#define NE 192     // 3*D
#define LDP 72     // padded LDS row stride (bf16 elems): 144B, 16B-aligned
#define WPS (64 * LDP + 8)   // proj w-plane stride: +8 de-phases wh-planes
// Q pre-scale: (1/8) * log2(e) -> softmax via exp2
#define QSCALE 0.1803368801111245f

__device__ __forceinline__ short f2bf(float f) {
  unsigned u = __float_as_uint(f);
  unsigned r = (u + 0x7FFFu + ((u >> 16) & 1u)) >> 16;
  return (short)r;
}

__device__ __forceinline__ bf16x8 pack8(float4 a, float4 b) {
  bf16x8 v;
  v[0] = f2bf(a.x); v[1] = f2bf(a.y); v[2] = f2bf(a.z); v[3] = f2bf(a.w);
  v[4] = f2bf(b.x); v[5] = f2bf(b.y); v[6] = f2bf(b.z); v[7] = f2bf(b.w);
  return v;
}

__device__ __forceinline__ short2 pk_bf16(float a, float b) {
  __hip_bfloat162 c = __float22bfloat162_rn(make_float2(a, b));
  return *reinterpret_cast<short2*>(&c);
}

// ---------------------------------------------------------------------------
// Kernel 1: QKV projection. Grid 512 = 64 bh x 8 groups; each block stages
// w[h] ONCE (permuted pi(e)=(e%3)*64+e/3 -> n-tiles 0-3 Q, 4-7 K, 8-11 V),
// then loops 4 row-tiles of 64 with x ping-pong prefetch. Q/K stored direct
// from regs; V transposed via per-wave LDS.
// ---------------------------------------------------------------------------
__global__ __launch_bounds__(256, 2) void proj_kernel(
    const float* __restrict__ x, const float* __restrict__ w,
    const float* __restrict__ bq, short* __restrict__ Qg,
    short* __restrict__ Kg, short* __restrict__ Vtg) {
  __shared__ short wt[3 * WPS];         // permuted w^T: [wh][dd][d]
  __shared__ short sV[4][64 * 24];      // per-wave V staging [d][row(16)] pad 24

  const int tid = threadIdx.x;
  const int bh = blockIdx.x >> 3;       // 64 heads
  const int g = blockIdx.x & 7;         // 8 groups of 4 row-tiles
  const int h = bh & 15;

  // stage w[h] -> permuted transposed bf16 in LDS (once per block)
  const float* whp = w + (size_t)h * DD * NE;
  for (int i = 0; i < 48; ++i) {
    int idx = i * 256 + tid;              // 12288 = 64*192, coalesced read
    int d = idx / NE, e = idx - d * NE;
    int dd = e / 3, wh = e - dd * 3;
    wt[wh * WPS + dd * LDP + d] = f2bf(whp[idx]);
  }
  __syncthreads();

  const int wave = tid >> 6;
  const int lane = tid & 63;
  const int col = lane & 15, quad = lane >> 4;
  const float* bqh = bq + h * NE;
  short* sVw = sV[wave];

  // A-frag loader for sub-tile i: A[m=col][k=quad*8+j]
  auto load_x = [&](int i, bf16x8 dst[2]) {
    int row0 = (g * 4 + i) * 64 + wave * 16;
    const float* xrow = x + ((size_t)bh * NQ + row0 + col) * DD;
#pragma unroll
    for (int kc = 0; kc < 2; ++kc) {
      const float4* p4 = (const float4*)(xrow + kc * 32 + quad * 8);
      dst[kc] = pack8(p4[0], p4[1]);
    }
  };

  bf16x8 aq[2][2];
  load_x(0, aq[0]);

#pragma unroll
  for (int i = 0; i < 4; ++i) {
    if (i < 3) load_x(i + 1, aq[(i + 1) & 1]);
    const bf16x8* a = aq[i & 1];
    const int row0 = (g * 4 + i) * 64 + wave * 16;

    f32x4 acc[12];
#pragma unroll
    for (int nt = 0; nt < 12; ++nt) acc[nt] = (f32x4){0.f, 0.f, 0.f, 0.f};

#pragma unroll
    for (int nt = 0; nt < 12; ++nt) {
      const short* wrow = &wt[(nt >> 2) * WPS + ((nt & 3) * 16 + col) * LDP];
#pragma unroll
      for (int kc = 0; kc < 2; ++kc) {
        bf16x8 bw = *(const bf16x8*)(wrow + kc * 32 + quad * 8);
        acc[nt] = __builtin_amdgcn_mfma_f32_16x16x32_bf16(a[kc], bw, acc[nt], 0, 0, 0);
      }
    }

    // epilogue: bias, packed cvt, branch-free de-interleave
    short* Qp = Qg + ((size_t)bh * NQ + row0) * DD;
    short* Kp = Kg + ((size_t)bh * NQ + row0) * DD;
#pragma unroll
    for (int nt = 0; nt < 12; ++nt) {
      int dd = (nt & 3) * 16 + col;             // within-matrix column, 0..63
      float bias = bqh[dd * 3 + (nt >> 2)];
      float v0 = acc[nt][0] + bias, v1 = acc[nt][1] + bias;
      float v2 = acc[nt][2] + bias, v3 = acc[nt][3] + bias;
      if (nt < 4) { v0 *= QSCALE; v1 *= QSCALE; v2 *= QSCALE; v3 *= QSCALE; }
      short2 s01 = pk_bf16(v0, v1);
      short2 s23 = pk_bf16(v2, v3);
      int rowl = quad * 4;
      if (nt < 4) {
        Qp[rowl * DD + dd] = s01.x; Qp[(rowl + 1) * DD + dd] = s01.y;
        Qp[(rowl + 2) * DD + dd] = s23.x; Qp[(rowl + 3) * DD + dd] = s23.y;
      } else if (nt < 8) {
        Kp[rowl * DD + dd] = s01.x; Kp[(rowl + 1) * DD + dd] = s01.y;
        Kp[(rowl + 2) * DD + dd] = s23.x; Kp[(rowl + 3) * DD + dd] = s23.y;
      } else {
        sVw[dd * 24 + rowl] = s01.x; sVw[dd * 24 + rowl + 1] = s01.y;
        sVw[dd * 24 + rowl + 2] = s23.x; sVw[dd * 24 + rowl + 3] = s23.y;
      }
    }

    // drain V (in-wave LDS write->read ordering)
    short* Vp = Vtg + (size_t)bh * DD * NQ + row0;
#pragma unroll
    for (int c = 0; c < 2; ++c) {
      int idx = c * 64 + lane;   // 0..127 = 64 d-rows x 2 halves
      int d = idx >> 1, half = (idx & 1) * 8;
      *(bf16x8*)(Vp + (size_t)d * NQ + half) = *(const bf16x8*)(sVw + d * 24 + half);
    }
  }
}

// ---------------------------------------------------------------------------
// Kernel 2: flash attention, barrier-free (R3 structure, proven correct) +
// XCD-local map (bh=blk&63: all 16 q-blocks of a head on one XCD; 8 heads x
// 512KB K/V = 4MB = L2) + register ping-pong prefetch of next tile's K/V
// fragments from global/L2 (frees the DS pipe: LDS = per-wave P buffer only).
// 2 waves x 64 q, grid 1024. S^T = K*Q^T -> exp2 -> b64 P-writes -> b128
// A-layout reads -> O += P*V. No __syncthreads.
// ---------------------------------------------------------------------------
__global__ __launch_bounds__(128, 2) void attn_kernel(
    const short* __restrict__ Qg, const short* __restrict__ Kg,
    const short* __restrict__ Vtg, float* __restrict__ out) {
  __shared__ short pbuf[2][64 * LDP];  // per-wave P [q][key]

  const int tid = threadIdx.x;
  const int bh = blockIdx.x & 63;      // XCD-local: head pinned to blk%8's XCD
  const int qb = blockIdx.x >> 6;      // 16 q-blocks per head
  const int wave = tid >> 6, lane = tid & 63;
  const int col = lane & 15, quad = lane >> 4;
  const int qbase = qb * 128 + wave * 64;

  // Q fragments (B-operand for S^T): B[n=q][k=d], persistent
  bf16x8 bqf[4][2];
#pragma unroll
  for (int ntq = 0; ntq < 4; ++ntq)
#pragma unroll
    for (int kc = 0; kc < 2; ++kc)
      bqf[ntq][kc] = *(const bf16x8*)(Qg + ((size_t)bh * NQ + qbase + ntq * 16 + col) * DD +
                                      kc * 32 + quad * 8);

  f32x4 o[4][4];
  float l_acc[4];
#pragma unroll
  for (int mtq = 0; mtq < 4; ++mtq) {
    l_acc[mtq] = 0.f;
#pragma unroll
    for (int ntd = 0; ntd < 4; ++ntd) o[mtq][ntd] = (f32x4){0.f, 0.f, 0.f, 0.f};
  }

  short* pb = pbuf[wave];
  const short* Kb = Kg + (size_t)bh * NQ * DD;
  const short* Vb = Vtg + (size_t)bh * DD * NQ;

  // double-buffered K/V fragment registers
  bf16x8 ka[2][4][2], vf[2][4][2];

  auto load_tile = [&](int t, int buf) {
    const short* Kt = Kb + t * 64 * DD;
    const short* Vt = Vb + t * 64;
#pragma unroll
    for (int mt = 0; mt < 4; ++mt)
#pragma unroll
      for (int kc = 0; kc < 2; ++kc) {
        ka[buf][mt][kc] = *(const bf16x8*)(Kt + (mt * 16 + col) * DD + kc * 32 + quad * 8);
        vf[buf][mt][kc] = *(const bf16x8*)(Vt + (size_t)(mt * 16 + col) * NQ + kc * 32 + quad * 8);
      }
  };

  auto compute = [&](int t, int buf, bool pf) {
    if (pf) load_tile(t + 1, buf ^ 1);

    // ---- S^T = K*Q^T, exp2, b64 P-writes ----
#pragma unroll
    for (int mtk = 0; mtk < 4; ++mtk) {
#pragma unroll
      for (int ntq = 0; ntq < 4; ++ntq) {
        f32x4 s = (f32x4){0.f, 0.f, 0.f, 0.f};
        s = __builtin_amdgcn_mfma_f32_16x16x32_bf16(ka[buf][mtk][0], bqf[ntq][0], s, 0, 0, 0);
        s = __builtin_amdgcn_mfma_f32_16x16x32_bf16(ka[buf][mtk][1], bqf[ntq][1], s, 0, 0, 0);
        // lane holds S^T[key=quad*4+r][q=ntq*16+col]
        float p0 = __builtin_amdgcn_exp2f(s[0]);
        float p1 = __builtin_amdgcn_exp2f(s[1]);
        float p2 = __builtin_amdgcn_exp2f(s[2]);
        float p3 = __builtin_amdgcn_exp2f(s[3]);
        l_acc[ntq] += (p0 + p1) + (p2 + p3);
        short2 s01 = pk_bf16(p0, p1);
        short2 s23 = pk_bf16(p2, p3);
        bf16x4 pv; pv[0] = s01.x; pv[1] = s01.y; pv[2] = s23.x; pv[3] = s23.y;
        *(bf16x4*)(&pb[(ntq * 16 + col) * LDP + mtk * 16 + quad * 4]) = pv;
      }
    }

    // ---- O += P*V ----
#pragma unroll
    for (int mtq = 0; mtq < 4; ++mtq) {
      bf16x8 ap0 = *(const bf16x8*)(&pb[(mtq * 16 + col) * LDP + quad * 8]);
      bf16x8 ap1 = *(const bf16x8*)(&pb[(mtq * 16 + col) * LDP + 32 + quad * 8]);
#pragma unroll
      for (int ntd = 0; ntd < 4; ++ntd) {
        o[mtq][ntd] = __builtin_amdgcn_mfma_f32_16x16x32_bf16(ap0, vf[buf][ntd][0], o[mtq][ntd], 0, 0, 0);
        o[mtq][ntd] = __builtin_amdgcn_mfma_f32_16x16x32_bf16(ap1, vf[buf][ntd][1], o[mtq][ntd], 0, 0, 0);
      }
    }
  };

  load_tile(0, 0);
#pragma unroll 1
  for (int tt = 0; tt < 16; ++tt) {
    compute(2 * tt, 0, true);
    compute(2 * tt + 1, 1, tt < 15);
  }

  // epilogue: reduce l across quads, normalize, store fp32 (R3-proven)
#pragma unroll
  for (int mtq = 0; mtq < 4; ++mtq) {
    float l = l_acc[mtq];
    l += __shfl_xor(l, 16);
    l += __shfl_xor(l, 32);   // lane now has total l for q = mtq*16 + col
#pragma unroll
    for (int r = 0; r < 4; ++r) {
      float inv = 1.0f / __shfl(l, quad * 4 + r);
      int rq = qbase + mtq * 16 + quad * 4 + r;
      float* orow = out + ((size_t)bh * NQ + rq) * DD;
#pragma unroll
      for (int ntd = 0; ntd < 4; ++ntd) orow[ntd * 16 + col] = o[mtq][ntd][r] * inv;
    }
  }
}

extern "C" void kernel_launch(void* const* d_in, const int* in_sizes, int n_in,
                              void* d_out, int out_size, void* d_ws, size_t ws_size,
                              hipStream_t stream) {
  const float* x = (const float*)d_in[0];    // [4,16,2048,64] fp32
  const float* w = (const float*)d_in[1];    // [16,64,192] fp32
  const float* bq = (const float*)d_in[2];   // [16,1,192] fp32
  float* out = (float*)d_out;                // [4,16,2048,64] fp32

  short* Qg = (short*)d_ws;                          // bf16 [64][2048][64], pre-scaled
  short* Kg = Qg + (size_t)BHC * NQ * DD;            // bf16 [64][2048][64]
  short* Vtg = Kg + (size_t)BHC * NQ * DD;           // bf16 [64][64][2048]

  proj_kernel<<<dim3(512), dim3(256), 0, stream>>>(x, w, bq, Qg, Kg, Vtg);
  attn_kernel<<<dim3(1024), dim3(128), 0, stream>>>(Qg, Kg, Vtg, out);
}

// Round 8
// 180.164 us; speedup vs baseline: 1.6860x; 1.6860x over previous
//
#include <hip/hip_runtime.h>
#include <hip/hip_bf16.h>
#include <stdint.h>

typedef short bf16x8 __attribute__((ext_vector_type(8)));
typedef short bf16x4 __attribute__((ext_vector_type(4)));
typedef float f32x4 __attribute__((ext_vector_type(4)));

#define BHC 64     // B*H
#define NQ 2048    // sequence length
#define DD 64      // head dim
#define NE 192     // 3*D
#define LDP 72     // padded LDS row stride (bf16 elems) for proj w / sV / pbuf
#define WPS (64 * LDP + 8)   // proj w-plane stride: +8 de-phases wh-planes
// Q pre-scale: (1/8) * log2(e) -> softmax via exp2
#define QSCALE 0.1803368801111245f

__device__ __forceinline__ short f2bf(float f) {
  unsigned u = __float_as_uint(f);
  unsigned r = (u + 0x7FFFu + ((u >> 16) & 1u)) >> 16;
  return (short)r;
}

__device__ __forceinline__ bf16x8 pack8(float4 a, float4 b) {
  bf16x8 v;
  v[0] = f2bf(a.x); v[1] = f2bf(a.y); v[2] = f2bf(a.z); v[3] = f2bf(a.w);
  v[4] = f2bf(b.x); v[5] = f2bf(b.y); v[6] = f2bf(b.z); v[7] = f2bf(b.w);
  return v;
}

__device__ __forceinline__ short2 pk_bf16(float a, float b) {
  __hip_bfloat162 c = __float22bfloat162_rn(make_float2(a, b));
  return *reinterpret_cast<short2*>(&c);
}

// ---------------------------------------------------------------------------
// Kernel 1: QKV projection (R6-proven, 84.8 us). w staged permuted
// (pi(e)=(e%3)*64+e/3): MFMA n-tiles 0-3 pure Q, 4-7 K, 8-11 V. Q/K stored
// direct from regs; V transposed via per-wave LDS.
// ---------------------------------------------------------------------------
__global__ __launch_bounds__(256, 4) void proj_kernel(
    const float* __restrict__ x, const float* __restrict__ w,
    const float* __restrict__ bq, short* __restrict__ Qg,
    short* __restrict__ Kg, short* __restrict__ Vtg) {
  __shared__ short wt[3 * WPS];         // permuted w^T: [wh][dd][d]
  __shared__ short sV[4][64 * 24];      // per-wave V staging [d][row(16)] pad 24

  const int tid = threadIdx.x;
  const int bh = blockIdx.x >> 5;  // 32 row-blocks per bh
  const int rb = blockIdx.x & 31;
  const int h = bh & 15;

  const float* whp = w + (size_t)h * DD * NE;
  for (int i = 0; i < 48; ++i) {
    int idx = i * 256 + tid;              // 12288 = 64*192, coalesced read
    int d = idx / NE, e = idx - d * NE;
    int dd = e / 3, wh = e - dd * 3;
    wt[wh * WPS + dd * LDP + d] = f2bf(whp[idx]);
  }
  __syncthreads();

  const int wave = tid >> 6;
  const int lane = tid & 63;
  const int col = lane & 15, quad = lane >> 4;
  const int row0 = rb * 64 + wave * 16;

  const float* xrow = x + ((size_t)bh * NQ + row0 + col) * DD;
  bf16x8 aq[2];
#pragma unroll
  for (int kc = 0; kc < 2; ++kc) {
    const float4* p4 = (const float4*)(xrow + kc * 32 + quad * 8);
    aq[kc] = pack8(p4[0], p4[1]);
  }

  f32x4 acc[12];
#pragma unroll
  for (int nt = 0; nt < 12; ++nt) acc[nt] = (f32x4){0.f, 0.f, 0.f, 0.f};

#pragma unroll
  for (int nt = 0; nt < 12; ++nt) {
    const short* wrow = &wt[(nt >> 2) * WPS + ((nt & 3) * 16 + col) * LDP];
#pragma unroll
    for (int kc = 0; kc < 2; ++kc) {
      bf16x8 bw = *(const bf16x8*)(wrow + kc * 32 + quad * 8);
      acc[nt] = __builtin_amdgcn_mfma_f32_16x16x32_bf16(aq[kc], bw, acc[nt], 0, 0, 0);
    }
  }

  const float* bqh = bq + h * NE;
  short* Qp = Qg + ((size_t)bh * NQ + row0) * DD;
  short* Kp = Kg + ((size_t)bh * NQ + row0) * DD;
  short* sVw = sV[wave];

#pragma unroll
  for (int nt = 0; nt < 12; ++nt) {
    int dd = (nt & 3) * 16 + col;               // within-matrix column, 0..63
    float bias = bqh[dd * 3 + (nt >> 2)];
    float v0 = acc[nt][0] + bias, v1 = acc[nt][1] + bias;
    float v2 = acc[nt][2] + bias, v3 = acc[nt][3] + bias;
    if (nt < 4) { v0 *= QSCALE; v1 *= QSCALE; v2 *= QSCALE; v3 *= QSCALE; }
    short2 s01 = pk_bf16(v0, v1);
    short2 s23 = pk_bf16(v2, v3);
    int rowl = quad * 4;
    if (nt < 4) {
      Qp[rowl * DD + dd] = s01.x; Qp[(rowl + 1) * DD + dd] = s01.y;
      Qp[(rowl + 2) * DD + dd] = s23.x; Qp[(rowl + 3) * DD + dd] = s23.y;
    } else if (nt < 8) {
      Kp[rowl * DD + dd] = s01.x; Kp[(rowl + 1) * DD + dd] = s01.y;
      Kp[(rowl + 2) * DD + dd] = s23.x; Kp[(rowl + 3) * DD + dd] = s23.y;
    } else {
      sVw[dd * 24 + rowl] = s01.x; sVw[dd * 24 + rowl + 1] = s01.y;
      sVw[dd * 24 + rowl + 2] = s23.x; sVw[dd * 24 + rowl + 3] = s23.y;
    }
  }

  short* Vp = Vtg + (size_t)bh * DD * NQ + row0;
#pragma unroll
  for (int c = 0; c < 2; ++c) {
    int idx = c * 64 + lane;     // 0..127 = 64 d-rows x 2 halves
    int d = idx >> 1, half = (idx & 1) * 8;
    *(bf16x8*)(Vp + (size_t)d * NQ + half) = *(const bf16x8*)(sVw + d * 24 + half);
  }
}

// ---------------------------------------------------------------------------
// Kernel 2: flash attention. R4 structure (proven 101 us: 4 waves x 64 q,
// LDS dbuf K/V staging, FULL-64-key P per wave for max ILP, one barrier/tile,
// l via VALU+shuffle) + R6's proven wins: XCD-local map (bh=blk&63; 8 heads
// x 512KB K/V = 4MB = one XCD's L2) and XOR-swizzled unpadded K/V buffers
// (conflicts = 0). Grid 512 = 2 blocks/CU. LDS 69.7 KB.
// ---------------------------------------------------------------------------
__global__ __launch_bounds__(256, 2) void attn_kernel(
    const short* __restrict__ Qg, const short* __restrict__ Kg,
    const short* __restrict__ Vtg, float* __restrict__ out) {
  __shared__ short kbuf[2][64 * 64];    // K tile  [key][d], XOR-swizzled
  __shared__ short vbuf[2][64 * 64];    // V^T tile [d][key], XOR-swizzled
  __shared__ short pbuf[4][64 * LDP];   // per-wave P [q][key(64)]

  const int tid = threadIdx.x;
  const int bh = blockIdx.x & 63;       // XCD-local: head pinned to blk%8's XCD
  const int qb = blockIdx.x >> 6;       // 8 q-blocks of 256 per head
  const int wave = tid >> 6, lane = tid & 63;
  const int col = lane & 15, quad = lane >> 4;
  const int qbase = qb * 256 + wave * 64;

  // Q fragments (B-operand for S^T): B[n=q][k=d], persistent in VGPRs
  bf16x8 bqf[4][2];
#pragma unroll
  for (int ntq = 0; ntq < 4; ++ntq)
#pragma unroll
    for (int kc = 0; kc < 2; ++kc)
      bqf[ntq][kc] = *(const bf16x8*)(Qg + ((size_t)bh * NQ + qbase + ntq * 16 + col) * DD +
                                      kc * 32 + quad * 8);

  f32x4 o[4][4];
  float l_acc[4];
#pragma unroll
  for (int mtq = 0; mtq < 4; ++mtq) {
    l_acc[mtq] = 0.f;
#pragma unroll
    for (int ntd = 0; ntd < 4; ++ntd) o[mtq][ntd] = (f32x4){0.f, 0.f, 0.f, 0.f};
  }

  short* pb = pbuf[wave];
  const short* Kb = Kg + (size_t)bh * NQ * DD;
  const short* Vb = Vtg + (size_t)bh * DD * NQ;

  // staging: 2 K-chunks + 2 V-chunks of 16B per thread; dst chunk ^= row&7
  const int r0 = tid >> 3, c0 = tid & 7;
  const int dst0 = r0 * 64 + ((c0 ^ (r0 & 7)) * 8);
  const int dst1 = (r0 + 32) * 64 + ((c0 ^ (r0 & 7)) * 8);  // (r0+32)&7 == r0&7
  const int src0 = r0 * DD + c0 * 8;
  const size_t vsrc0o = (size_t)r0 * NQ + c0 * 8;
  const size_t vsrc1o = (size_t)(r0 + 32) * NQ + c0 * 8;

  // prologue: stage tile 0 into buffer 0
  {
    bf16x8 k0 = *(const bf16x8*)(Kb + src0);
    bf16x8 k1 = *(const bf16x8*)(Kb + src0 + 32 * DD);
    bf16x8 v0 = *(const bf16x8*)(Vb + vsrc0o);
    bf16x8 v1 = *(const bf16x8*)(Vb + vsrc1o);
    *(bf16x8*)(&kbuf[0][dst0]) = k0;
    *(bf16x8*)(&kbuf[0][dst1]) = k1;
    *(bf16x8*)(&vbuf[0][dst0]) = v0;
    *(bf16x8*)(&vbuf[0][dst1]) = v1;
  }
  __syncthreads();

#pragma unroll 1
  for (int t = 0; t < 32; ++t) {
    const int p = t & 1;
    const short* kb = kbuf[p];
    const short* vb_s = vbuf[p];

    // prefetch next tile into regs (4 x bf16x8 = 16 VGPRs; in flight during compute)
    bf16x8 nk0, nk1, nv0, nv1;
    if (t < 31) {
      const short* Kn = Kb + (t + 1) * 64 * DD;
      const short* Vn = Vb + (t + 1) * 64;
      nk0 = *(const bf16x8*)(Kn + src0);
      nk1 = *(const bf16x8*)(Kn + src0 + 32 * DD);
      nv0 = *(const bf16x8*)(Vn + vsrc0o);
      nv1 = *(const bf16x8*)(Vn + vsrc1o);
    }

    // ---- S^T = K*Q^T over all 64 keys, exp2, b64 P-writes ----
#pragma unroll
    for (int mtk = 0; mtk < 4; ++mtk) {
      const int krow = mtk * 16 + col;
      const int kx = krow & 7;
      bf16x8 ka0 = *(const bf16x8*)(&kb[krow * 64 + ((quad ^ kx) * 8)]);
      bf16x8 ka1 = *(const bf16x8*)(&kb[krow * 64 + (((4 + quad) ^ kx) * 8)]);
#pragma unroll
      for (int ntq = 0; ntq < 4; ++ntq) {
        f32x4 s = (f32x4){0.f, 0.f, 0.f, 0.f};
        s = __builtin_amdgcn_mfma_f32_16x16x32_bf16(ka0, bqf[ntq][0], s, 0, 0, 0);
        s = __builtin_amdgcn_mfma_f32_16x16x32_bf16(ka1, bqf[ntq][1], s, 0, 0, 0);
        // lane holds S^T[key=mtk*16+quad*4+r][q=ntq*16+col]
        float p0 = __builtin_amdgcn_exp2f(s[0]);
        float p1 = __builtin_amdgcn_exp2f(s[1]);
        float p2 = __builtin_amdgcn_exp2f(s[2]);
        float p3 = __builtin_amdgcn_exp2f(s[3]);
        l_acc[ntq] += (p0 + p1) + (p2 + p3);
        short2 s01 = pk_bf16(p0, p1);
        short2 s23 = pk_bf16(p2, p3);
        bf16x4 pv; pv[0] = s01.x; pv[1] = s01.y; pv[2] = s23.x; pv[3] = s23.y;
        *(bf16x4*)(&pb[(ntq * 16 + col) * LDP + mtk * 16 + quad * 4]) = pv;
      }
    }

    // ---- O += P*V (full 64-key K-dim, 32 MFMAs back-to-back) ----
#pragma unroll
    for (int mtq = 0; mtq < 4; ++mtq) {
      bf16x8 ap0 = *(const bf16x8*)(&pb[(mtq * 16 + col) * LDP + quad * 8]);
      bf16x8 ap1 = *(const bf16x8*)(&pb[(mtq * 16 + col) * LDP + 32 + quad * 8]);
#pragma unroll
      for (int ntd = 0; ntd < 4; ++ntd) {
        const int vrow = ntd * 16 + col;
        const int vx = vrow & 7;
        bf16x8 vf0 = *(const bf16x8*)(&vb_s[vrow * 64 + ((quad ^ vx) * 8)]);
        bf16x8 vf1 = *(const bf16x8*)(&vb_s[vrow * 64 + (((4 + quad) ^ vx) * 8)]);
        o[mtq][ntd] = __builtin_amdgcn_mfma_f32_16x16x32_bf16(ap0, vf0, o[mtq][ntd], 0, 0, 0);
        o[mtq][ntd] = __builtin_amdgcn_mfma_f32_16x16x32_bf16(ap1, vf1, o[mtq][ntd], 0, 0, 0);
      }
    }

    // write prefetched tile into the other buffer, single barrier
    if (t < 31) {
      short* kn = kbuf[1 - p];
      short* vn = vbuf[1 - p];
      *(bf16x8*)(&kn[dst0]) = nk0;
      *(bf16x8*)(&kn[dst1]) = nk1;
      *(bf16x8*)(&vn[dst0]) = nv0;
      *(bf16x8*)(&vn[dst1]) = nv1;
      __syncthreads();
    }
  }

  // epilogue: reduce l across quads, normalize, store fp32 (R4-proven)
#pragma unroll
  for (int mtq = 0; mtq < 4; ++mtq) {
    float l = l_acc[mtq];
    l += __shfl_xor(l, 16);
    l += __shfl_xor(l, 32);   // lane now has total l for q = mtq*16 + col
#pragma unroll
    for (int r = 0; r < 4; ++r) {
      float inv = 1.0f / __shfl(l, quad * 4 + r);
      int rq = qbase + mtq * 16 + quad * 4 + r;
      float* orow = out + ((size_t)bh * NQ + rq) * DD;
#pragma unroll
      for (int ntd = 0; ntd < 4; ++ntd) orow[ntd * 16 + col] = o[mtq][ntd][r] * inv;
    }
  }
}

extern "C" void kernel_launch(void* const* d_in, const int* in_sizes, int n_in,
                              void* d_out, int out_size, void* d_ws, size_t ws_size,
                              hipStream_t stream) {
  const float* x = (const float*)d_in[0];    // [4,16,2048,64] fp32
  const float* w = (const float*)d_in[1];    // [16,64,192] fp32
  const float* bq = (const float*)d_in[2];   // [16,1,192] fp32
  float* out = (float*)d_out;                // [4,16,2048,64] fp32

  short* Qg = (short*)d_ws;                          // bf16 [64][2048][64], pre-scaled
  short* Kg = Qg + (size_t)BHC * NQ * DD;            // bf16 [64][2048][64]
  short* Vtg = Kg + (size_t)BHC * NQ * DD;           // bf16 [64][64][2048]

  proj_kernel<<<dim3(2048), dim3(256), 0, stream>>>(x, w, bq, Qg, Kg, Vtg);
  attn_kernel<<<dim3(512), dim3(256), 0, stream>>>(Qg, Kg, Vtg, out);
}